// Round 1
// baseline (370.228 us; speedup 1.0000x reference)
//
#include <hip/hip_runtime.h>
#include <math.h>

#define NROWS 65536
#define NC    1000
#define NTH   21
// ws layout (floats): [0,N) unc | [N,2N) conf_signed | [2N,3N) logp
// then 88 bins (22 each: ac, au, ic, iu) | ce_sum | umin_bits | umax_bits

__device__ __forceinline__ void upd_max(float v, int i, float& m, int& mi) {
    if (v > m) { m = v; mi = i; }
}

__global__ void k0_init(float* bins, float* ce_sum, unsigned* umin_b, unsigned* umax_b) {
    int i = threadIdx.x;
    if (i < 88) bins[i] = 0.f;
    if (i == 88) *ce_sum = 0.f;
    if (i == 89) *umin_b = 0x7f800000u;  // +inf
    if (i == 90) *umax_b = 0u;
}

__global__ __launch_bounds__(256) void k1_rowstats(
        const float* __restrict__ logits, const int* __restrict__ labels,
        float* __restrict__ unc_o, float* __restrict__ confs_o, float* __restrict__ logp_o)
{
    const int wave = threadIdx.x >> 6;
    const int lane = threadIdx.x & 63;
    const int row  = (blockIdx.x << 2) + wave;
    const float4* rp = (const float4*)(logits + (size_t)row * NC);

    // 250 float4 per row; lane handles f4 indices lane, lane+64, lane+128, lane+192
    float4 r0 = rp[lane];
    float4 r1 = rp[lane + 64];
    float4 r2 = rp[lane + 128];
    float4 r3 = make_float4(-1e30f, -1e30f, -1e30f, -1e30f);
    if (lane < 250 - 192) r3 = rp[lane + 192];

    // local max + argmax (increasing index order => first-occurrence tie-break)
    float m = -1e30f; int mi = 0;
    int b0 = lane << 2;
    upd_max(r0.x, b0 + 0, m, mi); upd_max(r0.y, b0 + 1, m, mi);
    upd_max(r0.z, b0 + 2, m, mi); upd_max(r0.w, b0 + 3, m, mi);
    int b1 = (lane + 64) << 2;
    upd_max(r1.x, b1 + 0, m, mi); upd_max(r1.y, b1 + 1, m, mi);
    upd_max(r1.z, b1 + 2, m, mi); upd_max(r1.w, b1 + 3, m, mi);
    int b2 = (lane + 128) << 2;
    upd_max(r2.x, b2 + 0, m, mi); upd_max(r2.y, b2 + 1, m, mi);
    upd_max(r2.z, b2 + 2, m, mi); upd_max(r2.w, b2 + 3, m, mi);
    int b3 = (lane + 192) << 2;
    upd_max(r3.x, b3 + 0, m, mi); upd_max(r3.y, b3 + 1, m, mi);
    upd_max(r3.z, b3 + 2, m, mi); upd_max(r3.w, b3 + 3, m, mi);

    // wave butterfly argmax (prefer smaller index on ties)
    #pragma unroll
    for (int off = 1; off < 64; off <<= 1) {
        float om = __shfl_xor(m, off, 64);
        int   oi = __shfl_xor(mi, off, 64);
        if (om > m || (om == m && oi < mi)) { m = om; mi = oi; }
    }

    // exp sums; sentinel -1e30 underflows exp to 0, 0*(-1e30) = -0 (no NaN)
    float se = 0.f, sx = 0.f;
#define ACCUM(v) { float t_ = (v) - m; float e_ = __expf(t_); se += e_; sx = fmaf(e_, t_, sx); }
    ACCUM(r0.x) ACCUM(r0.y) ACCUM(r0.z) ACCUM(r0.w)
    ACCUM(r1.x) ACCUM(r1.y) ACCUM(r1.z) ACCUM(r1.w)
    ACCUM(r2.x) ACCUM(r2.y) ACCUM(r2.z) ACCUM(r2.w)
    ACCUM(r3.x) ACCUM(r3.y) ACCUM(r3.z) ACCUM(r3.w)
#undef ACCUM
    #pragma unroll
    for (int off = 1; off < 64; off <<= 1) {
        se += __shfl_xor(se, off, 64);
        sx += __shfl_xor(sx, off, 64);
    }

    float Z    = se;
    float logZ = logf(Z);
    float conf = 1.0f / Z;            // max prob = exp(m-m)/Z
    float uncv = logZ - sx / Z;       // entropy

    int label = labels[row];          // wave-uniform scalar load
    int f4 = label >> 2, slot = label & 3, it = f4 >> 6;
    float4 q = (it == 0) ? r0 : (it == 1) ? r1 : (it == 2) ? r2 : r3;
    float cand = (slot == 0) ? q.x : (slot == 1) ? q.y : (slot == 2) ? q.z : q.w;
    float xl = __shfl(cand, f4 & 63, 64);

    if (lane == 0) {
        unc_o[row]   = uncv;
        confs_o[row] = (mi == label) ? conf : -conf;  // sign carries accuracy bit
        logp_o[row]  = (xl - m) - logZ;
    }
}

__global__ __launch_bounds__(256) void k2_reduce(
        const float* __restrict__ unc, const float* __restrict__ logp,
        float* ce_sum, unsigned* umin_b, unsigned* umax_b)
{
    float mn = 1e30f, mx = -1e30f, s = 0.f;
    for (int i = blockIdx.x * 256 + threadIdx.x; i < NROWS; i += 256 * gridDim.x) {
        float u = unc[i];
        mn = fminf(mn, u); mx = fmaxf(mx, u); s += logp[i];
    }
    #pragma unroll
    for (int off = 1; off < 64; off <<= 1) {
        mn = fminf(mn, __shfl_xor(mn, off, 64));
        mx = fmaxf(mx, __shfl_xor(mx, off, 64));
        s += __shfl_xor(s, off, 64);
    }
    __shared__ float smn[4], smx[4], ss[4];
    int wave = threadIdx.x >> 6;
    if ((threadIdx.x & 63) == 0) { smn[wave] = mn; smx[wave] = mx; ss[wave] = s; }
    __syncthreads();
    if (threadIdx.x == 0) {
        mn = fminf(fminf(smn[0], smn[1]), fminf(smn[2], smn[3]));
        mx = fmaxf(fmaxf(smx[0], smx[1]), fmaxf(smx[2], smx[3]));
        s  = ss[0] + ss[1] + ss[2] + ss[3];
        atomicAdd(ce_sum, s);
        atomicMin(umin_b, __float_as_uint(mn));  // entropy > 0: uint order == float order
        atomicMax(umax_b, __float_as_uint(mx));
    }
}

__global__ __launch_bounds__(256) void k3_hist(
        const float* __restrict__ unc, const float* __restrict__ confs,
        const unsigned* __restrict__ umin_b, const unsigned* __restrict__ umax_b,
        float* __restrict__ bins)
{
    __shared__ float h[88];
    for (int i = threadIdx.x; i < 88; i += 256) h[i] = 0.f;
    __syncthreads();
    float umin = __uint_as_float(*umin_b);
    float umax = __uint_as_float(*umax_b);
    float du = umax - umin;

    int i = blockIdx.x * 256 + threadIdx.x;
    float u  = unc[i];
    float cs = confs[i];
    float conf = fabsf(cs);
    bool  acc  = cs > 0.f;
    float tu = tanhf(u);

    // bucket = smallest t with u <= umin + (t*0.05)*du ; 21 => never certain
    int b = NTH;
    #pragma unroll
    for (int t = NTH - 1; t >= 0; --t) {
        float th = umin + ((float)t * 0.05f) * du;
        if (u <= th) b = t;
    }
    float w = acc ? conf : (1.f - conf);
    int base = acc ? 0 : 44;
    atomicAdd(&h[base + b],       w * (1.f - tu));  // -> n_ac / n_ic (certain side)
    atomicAdd(&h[base + 22 + b],  w * tu);          // -> n_au / n_iu (uncertain side)
    __syncthreads();
    for (int i2 = threadIdx.x; i2 < 88; i2 += 256) {
        float v = h[i2];
        if (v != 0.f) atomicAdd(&bins[i2], v);
    }
}

__global__ void k4_final(const float* __restrict__ bins, const float* __restrict__ ce_sum,
                         float* __restrict__ out)
{
    if (threadIdx.x != 0 || blockIdx.x != 0) return;
    float tot_au = 0.f, tot_iu = 0.f;
    for (int b = 0; b < 22; ++b) { tot_au += bins[22 + b]; tot_iu += bins[66 + b]; }
    float cac = 0.f, cau = 0.f, cic = 0.f, ciu = 0.f;
    float avu[NTH];
    for (int t = 0; t < NTH; ++t) {
        cac += bins[t]; cau += bins[22 + t]; cic += bins[44 + t]; ciu += bins[66 + t];
        float nac = cac, nau = tot_au - cau, nic = cic, niu = tot_iu - ciu;
        avu[t] = (nac + niu) / (nac + nau + nic + niu + 1e-12f);
    }
    float auc = 0.f;
    for (int t = 0; t + 1 < NTH; ++t) auc += 0.5f * (avu[t + 1] + avu[t]) * 0.05f;
    float avu_loss = -3.0f * logf(auc + 1e-12f);
    float ce = -(*ce_sum) / (float)NROWS;
    out[0] = avu_loss + ce;
}

extern "C" void kernel_launch(void* const* d_in, const int* in_sizes, int n_in,
                              void* d_out, int out_size, void* d_ws, size_t ws_size,
                              hipStream_t stream)
{
    const float* logits = (const float*)d_in[0];
    const int*   labels = (const int*)d_in[1];
    float* ws    = (float*)d_ws;
    float* unc   = ws;
    float* confs = ws + NROWS;
    float* logp  = ws + 2 * NROWS;
    float* bins  = ws + 3 * NROWS;            // 88 floats
    float* ce_sum = bins + 88;
    unsigned* umin_b = (unsigned*)(ce_sum + 1);
    unsigned* umax_b = umin_b + 1;

    hipLaunchKernelGGL(k0_init, dim3(1), dim3(128), 0, stream, bins, ce_sum, umin_b, umax_b);
    hipLaunchKernelGGL(k1_rowstats, dim3(NROWS / 4), dim3(256), 0, stream,
                       logits, labels, unc, confs, logp);
    hipLaunchKernelGGL(k2_reduce, dim3(256), dim3(256), 0, stream,
                       unc, logp, ce_sum, umin_b, umax_b);
    hipLaunchKernelGGL(k3_hist, dim3(NROWS / 256), dim3(256), 0, stream,
                       unc, confs, umin_b, umax_b, bins);
    hipLaunchKernelGGL(k4_final, dim3(1), dim3(64), 0, stream,
                       bins, ce_sum, (float*)d_out);
}